// Round 2
// baseline (356.607 us; speedup 1.0000x reference)
//
#include <hip/hip_runtime.h>

// DeformMaxPool2d: B=16, C=64, D=256, K=2, S=2, P=0 -> HO=128.
// gather_idx (128*128*4 int32) is a PERMUTATION of 0..65535 (windows tile the
// plane exactly; both scramblers are bijections). Strategy: invert it once per
// launch into inv[pixel] -> output_pos (ushort, 128KB in d_ws), then stream x
// coalesced and scatter-max into a 64KB LDS output tile per (b,c) plane.

#define D_DIM     256
#define HO        128
#define PLANE_IN  (D_DIM * D_DIM)   // 65536 pixels per plane
#define PLANE_OUT (HO * HO)         // 16384 outputs per plane
#define NPLANES   (16 * 64)         // 1024 (b,c) planes
#define TPB       1024

// native vector types (HIP float4 is a class -> rejected by nontemporal builtins)
typedef float    f32x4 __attribute__((ext_vector_type(4)));
typedef unsigned short u16x4 __attribute__((ext_vector_type(4)));

// ---- sortable encoding: monotone float -> uint (handles negatives) ----
__device__ __forceinline__ unsigned int enc_f32(float f) {
    unsigned int b = __float_as_uint(f);
    return (b & 0x80000000u) ? ~b : (b | 0x80000000u);
}
__device__ __forceinline__ float dec_f32(unsigned int u) {
    unsigned int b = (u & 0x80000000u) ? (u & 0x7FFFFFFFu) : ~u;
    return __uint_as_float(b);
}

// ---- prep 1: init inv to 0xFFFF sentinel (guards non-bijection / poison) ----
__global__ void init_inv_kernel(unsigned int* __restrict__ inv32) {
    int t = blockIdx.x * blockDim.x + threadIdx.x;
    if (t < PLANE_IN / 2) inv32[t] = 0xFFFFFFFFu;
}

// ---- prep 2: scatter inverse permutation. element e of gather_idx belongs to
// output position e>>2; thread t handles elements [4t, 4t+4) -> out pos = t ----
__global__ void build_inv_kernel(const int* __restrict__ gidx,
                                 unsigned short* __restrict__ inv) {
    int t = blockIdx.x * blockDim.x + threadIdx.x;  // [0, 16384)
    if (t >= PLANE_OUT) return;
    int4 g = reinterpret_cast<const int4*>(gidx)[t];
    unsigned short o = (unsigned short)t;
    inv[g.x] = o; inv[g.y] = o; inv[g.z] = o; inv[g.w] = o;
}

// ---- main: one workgroup per (b,c) plane ----
__launch_bounds__(TPB)
__global__ void pool_scatter_kernel(const float* __restrict__ x,
                                    const unsigned short* __restrict__ inv,
                                    float* __restrict__ out) {
    __shared__ unsigned int so[PLANE_OUT];          // 64 KB
    const int tid = threadIdx.x;
    const int bc  = blockIdx.x;

    // 0 is below the encoding of every finite float (enc(-inf)=0x007FFFFF)
    #pragma unroll
    for (int i = tid; i < PLANE_OUT; i += TPB) so[i] = 0u;
    __syncthreads();

    const f32x4* x4  = reinterpret_cast<const f32x4*>(x + (size_t)bc * PLANE_IN);
    const u16x4* iv4 = reinterpret_cast<const u16x4*>(inv);

    #pragma unroll 4
    for (int i = tid; i < PLANE_IN / 4; i += TPB) {
        f32x4 xv = __builtin_nontemporal_load(&x4[i]);  // streamed once: keep L2 for inv
        u16x4 ov = iv4[i];
        if (ov.x != 0xFFFFu) atomicMax(&so[ov.x], enc_f32(xv.x));
        if (ov.y != 0xFFFFu) atomicMax(&so[ov.y], enc_f32(xv.y));
        if (ov.z != 0xFFFFu) atomicMax(&so[ov.z], enc_f32(xv.z));
        if (ov.w != 0xFFFFu) atomicMax(&so[ov.w], enc_f32(xv.w));
    }
    __syncthreads();

    f32x4* out4 = reinterpret_cast<f32x4*>(out + (size_t)bc * PLANE_OUT);
    #pragma unroll
    for (int i = tid; i < PLANE_OUT / 4; i += TPB) {
        unsigned int u0 = so[4 * i + 0], u1 = so[4 * i + 1];
        unsigned int u2 = so[4 * i + 2], u3 = so[4 * i + 3];
        f32x4 r = { dec_f32(u0), dec_f32(u1), dec_f32(u2), dec_f32(u3) };
        __builtin_nontemporal_store(r, &out4[i]);
    }
}

// ---- fallback (only if workspace is too small): direct gather ----
__global__ void pool_gather_kernel(const float* __restrict__ x,
                                   const int* __restrict__ gidx,
                                   float* __restrict__ out) {
    long long t = (long long)blockIdx.x * blockDim.x + threadIdx.x;
    if (t >= (long long)NPLANES * PLANE_OUT) return;
    int pos = (int)(t & (PLANE_OUT - 1));
    int bc  = (int)(t >> 14);
    int4 g = reinterpret_cast<const int4*>(gidx)[pos];
    const float* xp = x + (size_t)bc * PLANE_IN;
    float m = fmaxf(fmaxf(xp[g.x], xp[g.y]), fmaxf(xp[g.z], xp[g.w]));
    out[t] = m;
}

extern "C" void kernel_launch(void* const* d_in, const int* in_sizes, int n_in,
                              void* d_out, int out_size, void* d_ws, size_t ws_size,
                              hipStream_t stream) {
    const float* x    = (const float*)d_in[0];
    const int*   gidx = (const int*)d_in[1];
    float*       out  = (float*)d_out;

    if (ws_size >= (size_t)PLANE_IN * sizeof(unsigned short)) {
        unsigned short* inv = (unsigned short*)d_ws;
        // init 32768 uints (128KB of ushort sentinel)
        init_inv_kernel<<<(PLANE_IN / 2 + 255) / 256, 256, 0, stream>>>((unsigned int*)d_ws);
        // 16384 threads, one per output position (4 gather entries each)
        build_inv_kernel<<<PLANE_OUT / 256, 256, 0, stream>>>(gidx, inv);
        // one workgroup per (b,c) plane
        pool_scatter_kernel<<<NPLANES, TPB, 0, stream>>>(x, inv, out);
    } else {
        long long total = (long long)NPLANES * PLANE_OUT;
        pool_gather_kernel<<<(int)((total + 255) / 256), 256, 0, stream>>>(x, gidx, out);
    }
}